// Round 7
// baseline (379.292 us; speedup 1.0000x reference)
//
#include <hip/hip_runtime.h>

#define Bv 4
#define Tv 2048
#define Ev 1024
#define Hv 16
#define Sv 64

typedef __attribute__((ext_vector_type(8))) short bf16x8;
typedef __attribute__((ext_vector_type(4))) float f32x4;

__device__ __forceinline__ ushort f2bf(float f) {
    unsigned u = __float_as_uint(f);
    u = (u + 0x7FFFu + ((u >> 16) & 1u)) >> 16;
    return (ushort)u;
}
__device__ __forceinline__ unsigned pk2(float a, float b) {
    return (unsigned)f2bf(a) | ((unsigned)f2bf(b) << 16);
}
// round-half-up bf16 (2 VALU ops), for softmax weights
__device__ __forceinline__ ushort f2bf_rhu(float f) {
    return (ushort)((__float_as_uint(f) + 0x8000u) >> 16);
}

// async global->LDS, 16B per lane (global_load_lds_dwordx4)
__device__ __forceinline__ void async16(void* lds, const void* g) {
    __builtin_amdgcn_global_load_lds(
        (const __attribute__((address_space(1))) unsigned int*)g,
        (__attribute__((address_space(3))) unsigned int*)lds, 16, 0, 0);
}

// ---------------------------------------------------------------------------
// Kernel 0: cast weights fp32 -> bf16. Blocks 0..1023: Wp. 1024..1026: Wq/Wk/Wv
// Wq folded with (1/32)*log2(e): attn uses exp2 so v_exp_f32 needs no mul.
// ---------------------------------------------------------------------------
__global__ __launch_bounds__(256) void cast_kernel(
    const float* __restrict__ Wp, const float* __restrict__ Wq,
    const float* __restrict__ Wk, const float* __restrict__ Wv,
    ushort* __restrict__ Wpb, ushort* __restrict__ Wqb,
    ushort* __restrict__ Wkb, ushort* __restrict__ Wvb)
{
    int blk = blockIdx.x;
    if (blk < 1024) {
        int i = (blk * 256 + threadIdx.x) * 4;
        float4 v = *(const float4*)(Wp + i);
        ushort4 o;
        o.x = f2bf(v.x); o.y = f2bf(v.y); o.z = f2bf(v.z); o.w = f2bf(v.w);
        *(ushort4*)(Wpb + i) = o;
    } else {
        int p = blk - 1024;
        const float* src = (p == 0) ? Wq : ((p == 1) ? Wk : Wv);
        ushort* dst      = (p == 0) ? Wqb : ((p == 1) ? Wkb : Wvb);
        const float scale = (p == 0) ? 0.03125f * 1.4426950408889634f : 1.0f;
        #pragma unroll
        for (int it = 0; it < 4; ++it) {
            int i = (it * 256 + threadIdx.x) * 4;
            float4 v = *(const float4*)(src + i);
            ushort4 o;
            o.x = f2bf(v.x * scale); o.y = f2bf(v.y * scale);
            o.z = f2bf(v.z * scale); o.w = f2bf(v.w * scale);
            *(ushort4*)(dst + i) = o;
        }
    }
}

// ---------------------------------------------------------------------------
// Kernel 1: QKV projection via MFMA, no LDS. (unchanged from round 5)
// ---------------------------------------------------------------------------
__global__ __launch_bounds__(192) void qkv_kernel(
    const float* __restrict__ x,
    const ushort* __restrict__ Wqb, const ushort* __restrict__ Wkb,
    const ushort* __restrict__ Wvb,
    ushort* __restrict__ Q, ushort* __restrict__ K, ushort* __restrict__ Vt)
{
    const int tid  = threadIdx.x;
    const int wave = tid >> 6;        // 0=Q 1=K 2=V
    const int lane = tid & 63;
    const int m    = lane & 15;
    const int quad = lane >> 4;

    const ushort* Wsel = (wave == 0) ? Wqb : ((wave == 1) ? Wkb : Wvb);
    bf16x8 wf[4][2];
    #pragma unroll
    for (int ot = 0; ot < 4; ++ot)
        #pragma unroll
        for (int ks = 0; ks < 2; ++ks)
            wf[ot][ks] = *(const bf16x8*)&Wsel[(ot * 16 + m) * 64 + ks * 32 + quad * 8];

    const int tt = blockIdx.x >> 2;   // 0..511 token tile
    const int hg = blockIdx.x & 3;    // head group
    const int g0 = tt * 16;
    const int gm = g0 + m;
    const int b  = g0 >> 11;
    const int t0 = g0 & 2047;

    #pragma unroll
    for (int hi = 0; hi < 4; ++hi) {
        const int h  = hg * 4 + hi;
        const int bh = b * Hv + h;

        bf16x8 xf[2];
        #pragma unroll
        for (int ks = 0; ks < 2; ++ks) {
            const float* src = x + (size_t)gm * Ev + h * Sv + ks * 32 + quad * 8;
            float4 v0 = *(const float4*)src;
            float4 v1 = *(const float4*)(src + 4);
            unsigned pk[4];
            pk[0] = pk2(v0.x, v0.y); pk[1] = pk2(v0.z, v0.w);
            pk[2] = pk2(v1.x, v1.y); pk[3] = pk2(v1.z, v1.w);
            xf[ks] = *(bf16x8*)pk;
        }

        f32x4 acc[4];
        #pragma unroll
        for (int ot = 0; ot < 4; ++ot) acc[ot] = (f32x4){0.f, 0.f, 0.f, 0.f};

        if (wave < 2) {
            #pragma unroll
            for (int ks = 0; ks < 2; ++ks)
                #pragma unroll
                for (int ot = 0; ot < 4; ++ot)
                    acc[ot] = __builtin_amdgcn_mfma_f32_16x16x32_bf16(
                        wf[ot][ks], xf[ks], acc[ot], 0, 0, 0);
            ushort* dst = ((wave == 0) ? Q : K)
                        + ((size_t)bh * Tv + t0 + m) * Sv + quad * 4;
            #pragma unroll
            for (int ot = 0; ot < 4; ++ot) {
                uint2 w;
                w.x = pk2(acc[ot][0], acc[ot][1]);
                w.y = pk2(acc[ot][2], acc[ot][3]);
                *(uint2*)(dst + ot * 16) = w;
            }
        } else {
            #pragma unroll
            for (int ks = 0; ks < 2; ++ks)
                #pragma unroll
                for (int st = 0; st < 4; ++st)
                    acc[st] = __builtin_amdgcn_mfma_f32_16x16x32_bf16(
                        xf[ks], wf[st][ks], acc[st], 0, 0, 0);
            ushort* vr = Vt + ((size_t)bh * Sv + m) * Tv + t0 + quad * 4;
            #pragma unroll
            for (int st = 0; st < 4; ++st) {
                uint2 w;
                w.x = pk2(acc[st][0], acc[st][1]);
                w.y = pk2(acc[st][2], acc[st][3]);
                *(uint2*)(vr + (size_t)st * 16 * Tv) = w;
            }
        }
    }
}

// ---------------------------------------------------------------------------
// Kernel 2: flash attention v4 — ZERO barriers in the K-loop.
// B-frags for QK^T (K rows) and PV (Vt rows) load directly global->VGPR;
// no K/V LDS staging at all. The 4 waves of a block read the same tile ->
// L1 dedup; bh = blk&63 keeps each XCD's K/V working set == its 4MB L2.
// P round-trips wave-PRIVATE swizzled LDS (lgkmcnt-ordered, no barrier).
// With no __syncthreads, the compiler pipelines next-tile loads into the
// current tile's MFMA shadow — the async overlap R6's barrier version
// couldn't express (vmcnt(0) drain before s_barrier, m99/m131 disease).
// ---------------------------------------------------------------------------
__global__ __launch_bounds__(256, 4) void attn_kernel(
    const ushort* __restrict__ Q, const ushort* __restrict__ K,
    const ushort* __restrict__ Vt, ushort* __restrict__ O)
{
    __shared__ ushort pl[4][32 * 64];     // P per wave [q][key] (swizzled)

    const int tid  = threadIdx.x;
    const int wave = tid >> 6;
    const int lane = tid & 63;
    const int m    = lane & 15;
    const int quad = lane >> 4;
    const int bh   = blockIdx.x & 63;
    const int q0   = (blockIdx.x >> 6) << 7;   // query tile base (128)

    const ushort* Qb = Q + ((size_t)bh * Tv + q0 + wave * 32) * Sv;
    bf16x8 qf[2][2];
    #pragma unroll
    for (int g = 0; g < 2; ++g)
        #pragma unroll
        for (int ks = 0; ks < 2; ++ks)
            qf[g][ks] = *(const bf16x8*)&Qb[(g * 16 + m) * Sv + ks * 32 + quad * 8];

    f32x4 oa[2][4];
    float lsum[2][4];
    #pragma unroll
    for (int g = 0; g < 2; ++g)
        #pragma unroll
        for (int nt = 0; nt < 4; ++nt) {
            oa[g][nt] = (f32x4){0.f, 0.f, 0.f, 0.f};
            lsum[g][nt] = 0.f;
        }

    // per-lane row pointers: K row (key = nt*16+m), Vt row (s = nt*16+m)
    const ushort* Kb = K  + ((size_t)bh * Tv + m) * Sv;
    const ushort* Vb = Vt + ((size_t)bh * Sv + m) * Tv;
    ushort* pw = pl[wave];
    const int mx = m & 7;

    for (int k0 = 0; k0 < Tv; k0 += 64) {
        // QK^T + exp2 + P to wave-private LDS (B-frags direct from global)
        #pragma unroll
        for (int nt = 0; nt < 4; ++nt) {
            const ushort* krow = Kb + ((size_t)k0 + nt * 16) * Sv;
            bf16x8 b0 = *(const bf16x8*)(krow + quad * 8);
            bf16x8 b1 = *(const bf16x8*)(krow + 32 + quad * 8);
            #pragma unroll
            for (int g = 0; g < 2; ++g) {
                f32x4 s = (f32x4){0.f, 0.f, 0.f, 0.f};
                s = __builtin_amdgcn_mfma_f32_16x16x32_bf16(qf[g][0], b0, s, 0, 0, 0);
                s = __builtin_amdgcn_mfma_f32_16x16x32_bf16(qf[g][1], b1, s, 0, 0, 0);
                #pragma unroll
                for (int r = 0; r < 4; ++r) {
                    float p = __builtin_amdgcn_exp2f(s[r]);
                    lsum[g][r] += p;
                    const int qrow = quad * 4 + r;
                    pw[(g * 16 + qrow) * 64
                       + (((nt * 2 + (m >> 3)) ^ (qrow & 7)) * 8) + mx] = f2bf_rhu(p);
                }
            }
        }

        // PV: A from wave-private P LDS, B (Vt rows) direct from global
        bf16x8 af[2][2];
        #pragma unroll
        for (int g = 0; g < 2; ++g) {
            af[g][0] = *(const bf16x8*)&pw[(g * 16 + m) * 64 + ((quad       ^ mx) * 8)];
            af[g][1] = *(const bf16x8*)&pw[(g * 16 + m) * 64 + (((4 + quad) ^ mx) * 8)];
        }
        #pragma unroll
        for (int nt = 0; nt < 4; ++nt) {
            const ushort* vrow = Vb + (size_t)nt * 16 * Tv + k0;
            bf16x8 v0 = *(const bf16x8*)(vrow + quad * 8);
            bf16x8 v1 = *(const bf16x8*)(vrow + 32 + quad * 8);
            #pragma unroll
            for (int g = 0; g < 2; ++g) {
                oa[g][nt] = __builtin_amdgcn_mfma_f32_16x16x32_bf16(af[g][0], v0, oa[g][nt], 0, 0, 0);
                oa[g][nt] = __builtin_amdgcn_mfma_f32_16x16x32_bf16(af[g][1], v1, oa[g][nt], 0, 0, 0);
            }
        }
    }

    #pragma unroll
    for (int g = 0; g < 2; ++g)
        #pragma unroll
        for (int r = 0; r < 4; ++r) {
            #pragma unroll
            for (int d = 1; d < 16; d <<= 1)
                lsum[g][r] += __shfl_xor(lsum[g][r], d, 64);
            lsum[g][r] = 1.0f / lsum[g][r];
        }

    const int b = bh >> 4, h = bh & 15;
    #pragma unroll
    for (int g = 0; g < 2; ++g)
        #pragma unroll
        for (int nt = 0; nt < 4; ++nt)
            #pragma unroll
            for (int r = 0; r < 4; ++r)
                O[((size_t)(b * Tv + q0 + wave * 32 + g * 16 + quad * 4 + r)) * Ev
                  + h * Sv + nt * 16 + m] = f2bf(oa[g][nt][r] * lsum[g][r]);
}

// ---------------------------------------------------------------------------
// Kernel 3: output projection, bf16 MFMA (m97 structure). (unchanged)
// ---------------------------------------------------------------------------
__global__ __launch_bounds__(256) void proj_kernel(
    const ushort* __restrict__ A, const ushort* __restrict__ B,
    const float* __restrict__ bp, float* __restrict__ C)
{
    __shared__ ushort Asm[128 * 32];
    __shared__ ushort Bsm[128 * 32];
    const int tid  = threadIdx.x;
    const int wave = tid >> 6;
    const int lane = tid & 63;
    const int m    = lane & 15;
    const int quad = lane >> 4;
    const int wm   = wave >> 1;
    const int wn   = wave & 1;
    const int m0   = blockIdx.x * 128;
    const int n0   = blockIdx.y * 128;

    f32x4 acc[4][4];
    #pragma unroll
    for (int i = 0; i < 4; ++i)
        #pragma unroll
        for (int j = 0; j < 4; ++j)
            acc[i][j] = (f32x4){0.f, 0.f, 0.f, 0.f};

    for (int k0 = 0; k0 < Ev; k0 += 32) {
        __syncthreads();
        #pragma unroll
        for (int j = 0; j < 2; ++j) {
            int c   = j * 256 + tid;
            int row = c >> 2;
            int col = (c & 3) * 8;
            async16(&Asm[c * 8], &A[(size_t)(m0 + row) * Ev + k0 + col]);
            async16(&Bsm[c * 8], &B[(size_t)(n0 + row) * Ev + k0 + col]);
        }
        __syncthreads();

        bf16x8 af[4], bf[4];
        #pragma unroll
        for (int i = 0; i < 4; ++i)
            af[i] = *(const bf16x8*)&Asm[(wm * 64 + i * 16 + m) * 32 + quad * 8];
        #pragma unroll
        for (int j = 0; j < 4; ++j)
            bf[j] = *(const bf16x8*)&Bsm[(wn * 64 + j * 16 + m) * 32 + quad * 8];
        #pragma unroll
        for (int i = 0; i < 4; ++i)
            #pragma unroll
            for (int j = 0; j < 4; ++j)
                acc[i][j] = __builtin_amdgcn_mfma_f32_16x16x32_bf16(
                    af[i], bf[j], acc[i][j], 0, 0, 0);
    }

    float bbv[4];
    #pragma unroll
    for (int j = 0; j < 4; ++j)
        bbv[j] = bp[n0 + wn * 64 + j * 16 + m];

    #pragma unroll
    for (int i = 0; i < 4; ++i)
        #pragma unroll
        for (int j = 0; j < 4; ++j)
            #pragma unroll
            for (int r = 0; r < 4; ++r)
                C[(size_t)(m0 + wm * 64 + i * 16 + quad * 4 + r) * Ev
                  + n0 + wn * 64 + j * 16 + m] = acc[i][j][r] + bbv[j];
}

// ---------------------------------------------------------------------------
// ws layout (ushort units):
//   Q 8.4M | K 8.4M | Vt 8.4M | O 8.4M | Wpb 1M | Wqb 4096 | Wkb 4096 | Wvb 4096
// ---------------------------------------------------------------------------
extern "C" void kernel_launch(void* const* d_in, const int* in_sizes, int n_in,
                              void* d_out, int out_size, void* d_ws, size_t ws_size,
                              hipStream_t stream) {
    const float* x  = (const float*)d_in[0];
    const float* Wk = (const float*)d_in[1];
    const float* Wq = (const float*)d_in[2];
    const float* Wv = (const float*)d_in[3];
    const float* Wp = (const float*)d_in[4];
    const float* bp = (const float*)d_in[5];
    float* out = (float*)d_out;

    ushort* Q   = (ushort*)d_ws;
    ushort* K   = Q   + 8388608;
    ushort* Vt  = K   + 8388608;
    ushort* O   = Vt  + 8388608;
    ushort* Wpb = O   + 8388608;
    ushort* Wqb = Wpb + 1048576;
    ushort* Wkb = Wqb + 4096;
    ushort* Wvb = Wkb + 4096;

    cast_kernel<<<1027, 256, 0, stream>>>(Wp, Wq, Wk, Wv, Wpb, Wqb, Wkb, Wvb);
    qkv_kernel<<<2048, 192, 0, stream>>>(x, Wqb, Wkb, Wvb, Q, K, Vt);
    attn_kernel<<<1024, 256, 0, stream>>>(Q, K, Vt, O);
    proj_kernel<<<dim3(64, 8), 256, 0, stream>>>(O, Wpb, bp, out);
}

// Round 8
// 256.606 us; speedup vs baseline: 1.4781x; 1.4781x over previous
//
#include <hip/hip_runtime.h>

#define Bv 4
#define Tv 2048
#define Ev 1024
#define Hv 16
#define Sv 64

typedef __attribute__((ext_vector_type(8))) short bf16x8;
typedef __attribute__((ext_vector_type(4))) float f32x4;

__device__ __forceinline__ ushort f2bf(float f) {
    unsigned u = __float_as_uint(f);
    u = (u + 0x7FFFu + ((u >> 16) & 1u)) >> 16;
    return (ushort)u;
}
__device__ __forceinline__ unsigned pk2(float a, float b) {
    return (unsigned)f2bf(a) | ((unsigned)f2bf(b) << 16);
}
// round-half-up bf16 (2 VALU ops), for softmax weights
__device__ __forceinline__ ushort f2bf_rhu(float f) {
    return (ushort)((__float_as_uint(f) + 0x8000u) >> 16);
}

// async global->LDS, 16B per lane (global_load_lds_dwordx4)
__device__ __forceinline__ void async16(void* lds, const void* g) {
    __builtin_amdgcn_global_load_lds(
        (const __attribute__((address_space(1))) unsigned int*)g,
        (__attribute__((address_space(3))) unsigned int*)lds, 16, 0, 0);
}

// ---------------------------------------------------------------------------
// Kernel 0: cast weights fp32 -> bf16. Blocks 0..1023: Wp. 1024..1026: Wq/Wk/Wv
// Wq folded with (1/32)*log2(e): attn uses exp2 so v_exp_f32 needs no mul.
// ---------------------------------------------------------------------------
__global__ __launch_bounds__(256) void cast_kernel(
    const float* __restrict__ Wp, const float* __restrict__ Wq,
    const float* __restrict__ Wk, const float* __restrict__ Wv,
    ushort* __restrict__ Wpb, ushort* __restrict__ Wqb,
    ushort* __restrict__ Wkb, ushort* __restrict__ Wvb)
{
    int blk = blockIdx.x;
    if (blk < 1024) {
        int i = (blk * 256 + threadIdx.x) * 4;
        float4 v = *(const float4*)(Wp + i);
        ushort4 o;
        o.x = f2bf(v.x); o.y = f2bf(v.y); o.z = f2bf(v.z); o.w = f2bf(v.w);
        *(ushort4*)(Wpb + i) = o;
    } else {
        int p = blk - 1024;
        const float* src = (p == 0) ? Wq : ((p == 1) ? Wk : Wv);
        ushort* dst      = (p == 0) ? Wqb : ((p == 1) ? Wkb : Wvb);
        const float scale = (p == 0) ? 0.03125f * 1.4426950408889634f : 1.0f;
        #pragma unroll
        for (int it = 0; it < 4; ++it) {
            int i = (it * 256 + threadIdx.x) * 4;
            float4 v = *(const float4*)(src + i);
            ushort4 o;
            o.x = f2bf(v.x * scale); o.y = f2bf(v.y * scale);
            o.z = f2bf(v.z * scale); o.w = f2bf(v.w * scale);
            *(ushort4*)(dst + i) = o;
        }
    }
}

// ---------------------------------------------------------------------------
// Kernel 1: QKV projection via MFMA, no LDS. (unchanged from round 5)
// ---------------------------------------------------------------------------
__global__ __launch_bounds__(192) void qkv_kernel(
    const float* __restrict__ x,
    const ushort* __restrict__ Wqb, const ushort* __restrict__ Wkb,
    const ushort* __restrict__ Wvb,
    ushort* __restrict__ Q, ushort* __restrict__ K, ushort* __restrict__ Vt)
{
    const int tid  = threadIdx.x;
    const int wave = tid >> 6;        // 0=Q 1=K 2=V
    const int lane = tid & 63;
    const int m    = lane & 15;
    const int quad = lane >> 4;

    const ushort* Wsel = (wave == 0) ? Wqb : ((wave == 1) ? Wkb : Wvb);
    bf16x8 wf[4][2];
    #pragma unroll
    for (int ot = 0; ot < 4; ++ot)
        #pragma unroll
        for (int ks = 0; ks < 2; ++ks)
            wf[ot][ks] = *(const bf16x8*)&Wsel[(ot * 16 + m) * 64 + ks * 32 + quad * 8];

    const int tt = blockIdx.x >> 2;   // 0..511 token tile
    const int hg = blockIdx.x & 3;    // head group
    const int g0 = tt * 16;
    const int gm = g0 + m;
    const int b  = g0 >> 11;
    const int t0 = g0 & 2047;

    #pragma unroll
    for (int hi = 0; hi < 4; ++hi) {
        const int h  = hg * 4 + hi;
        const int bh = b * Hv + h;

        bf16x8 xf[2];
        #pragma unroll
        for (int ks = 0; ks < 2; ++ks) {
            const float* src = x + (size_t)gm * Ev + h * Sv + ks * 32 + quad * 8;
            float4 v0 = *(const float4*)src;
            float4 v1 = *(const float4*)(src + 4);
            unsigned pk[4];
            pk[0] = pk2(v0.x, v0.y); pk[1] = pk2(v0.z, v0.w);
            pk[2] = pk2(v1.x, v1.y); pk[3] = pk2(v1.z, v1.w);
            xf[ks] = *(bf16x8*)pk;
        }

        f32x4 acc[4];
        #pragma unroll
        for (int ot = 0; ot < 4; ++ot) acc[ot] = (f32x4){0.f, 0.f, 0.f, 0.f};

        if (wave < 2) {
            #pragma unroll
            for (int ks = 0; ks < 2; ++ks)
                #pragma unroll
                for (int ot = 0; ot < 4; ++ot)
                    acc[ot] = __builtin_amdgcn_mfma_f32_16x16x32_bf16(
                        wf[ot][ks], xf[ks], acc[ot], 0, 0, 0);
            ushort* dst = ((wave == 0) ? Q : K)
                        + ((size_t)bh * Tv + t0 + m) * Sv + quad * 4;
            #pragma unroll
            for (int ot = 0; ot < 4; ++ot) {
                uint2 w;
                w.x = pk2(acc[ot][0], acc[ot][1]);
                w.y = pk2(acc[ot][2], acc[ot][3]);
                *(uint2*)(dst + ot * 16) = w;
            }
        } else {
            #pragma unroll
            for (int ks = 0; ks < 2; ++ks)
                #pragma unroll
                for (int st = 0; st < 4; ++st)
                    acc[st] = __builtin_amdgcn_mfma_f32_16x16x32_bf16(
                        xf[ks], wf[st][ks], acc[st], 0, 0, 0);
            ushort* vr = Vt + ((size_t)bh * Sv + m) * Tv + t0 + quad * 4;
            #pragma unroll
            for (int st = 0; st < 4; ++st) {
                uint2 w;
                w.x = pk2(acc[st][0], acc[st][1]);
                w.y = pk2(acc[st][2], acc[st][3]);
                *(uint2*)(vr + (size_t)st * 16 * Tv) = w;
            }
        }
    }
}

// ---------------------------------------------------------------------------
// Kernel 2: flash attention v5 — R5 staging + DOUBLE-BUFFERED DMA with raw
// s_barrier / explicit vmcnt (AITER pattern). Per 64-key tile:
//   s_barrier                      (all waves done reading buf 1-c)
//   issue 4x global_load_lds -> buf 1-c  (tile i+1; stays in flight)
//   s_waitcnt vmcnt(4)             (own tile-i DMAs landed)
//   s_barrier                      (tile i visible to all)
//   compute tile i from buf c      (tile i+1 flying underneath)
// No vmcnt(0) drain anywhere: __syncthreads is never used in the loop.
// Compiler inserts no waits for DMA (no dest reg), so explicit ones stand.
// LDS 48KB -> 3 blocks/CU. XOR swizzle unchanged (conflict-free frag reads).
// ---------------------------------------------------------------------------
__global__ __launch_bounds__(256) void attn_kernel(
    const ushort* __restrict__ Q, const ushort* __restrict__ K,
    const ushort* __restrict__ Vt, ushort* __restrict__ O)
{
    __shared__ ushort kl[2][64 * 64];     // K tiles  [key][d]   (swizzled)
    __shared__ ushort vl[2][64 * 64];     // Vt tiles [s][key]   (swizzled)
    __shared__ ushort pl[4][32 * 64];     // P per wave [q][key] (swizzled)

    const int tid  = threadIdx.x;
    const int wave = tid >> 6;
    const int lane = tid & 63;
    const int m    = lane & 15;
    const int quad = lane >> 4;
    const int bh   = blockIdx.x & 63;
    const int q0   = (blockIdx.x >> 6) << 7;   // query tile base (128)

    const ushort* Qb = Q + ((size_t)bh * Tv + q0 + wave * 32) * Sv;
    bf16x8 qf[2][2];
    #pragma unroll
    for (int g = 0; g < 2; ++g)
        #pragma unroll
        for (int ks = 0; ks < 2; ++ks)
            qf[g][ks] = *(const bf16x8*)&Qb[(g * 16 + m) * Sv + ks * 32 + quad * 8];

    f32x4 oa[2][4];
    float lsum[2][4];
    #pragma unroll
    for (int g = 0; g < 2; ++g)
        #pragma unroll
        for (int nt = 0; nt < 4; ++nt) {
            oa[g][nt] = (f32x4){0.f, 0.f, 0.f, 0.f};
            lsum[g][nt] = 0.f;
        }

    const ushort* Kb = K  + (size_t)bh * Tv * Sv;
    const ushort* Vb = Vt + (size_t)bh * Sv * Tv;
    ushort* pw = pl[wave];

    // staging geometry (swizzled): chunk c -> row=c>>3, phys cg=c&7,
    // source col-group = (c&7) ^ (row&7)
    const int r0 = tid >> 3,         cg0 = (tid & 7) ^ (r0 & 7);
    const int r1 = (256 + tid) >> 3, cg1 = ((256 + tid) & 7) ^ (r1 & 7);
    const size_t koff0 = (size_t)r0 * Sv + cg0 * 8;
    const size_t koff1 = (size_t)r1 * Sv + cg1 * 8;
    const size_t voff0 = (size_t)r0 * Tv + cg0 * 8;
    const size_t voff1 = (size_t)r1 * Tv + cg1 * 8;
    const int mx = m & 7;

    // prologue: DMA tile 0 -> buffer 0 (4 loads/lane in flight)
    async16(&kl[0][(size_t)tid * 8],         Kb + koff0);
    async16(&kl[0][((size_t)tid + 256) * 8], Kb + koff1);
    async16(&vl[0][(size_t)tid * 8],         Vb + voff0);
    async16(&vl[0][((size_t)tid + 256) * 8], Vb + voff1);

    for (int k0 = 0; k0 < Tv; k0 += 64) {
        const int c = (k0 >> 6) & 1;

        // all waves finished READING buf 1-c (tile i-1) before we DMA into it
        __builtin_amdgcn_s_barrier();

        // issue DMA for tile i+1 into buf 1-c (wraps at end; harmless)
        const int kn = (k0 + 64 < Tv) ? k0 + 64 : 0;
        async16(&kl[1 - c][(size_t)tid * 8],         Kb + (size_t)kn * Sv + koff0);
        async16(&kl[1 - c][((size_t)tid + 256) * 8], Kb + (size_t)kn * Sv + koff1);
        async16(&vl[1 - c][(size_t)tid * 8],         Vb + kn + voff0);
        async16(&vl[1 - c][((size_t)tid + 256) * 8], Vb + kn + voff1);

        // own tile-i DMAs (issued last iter / prologue) have landed;
        // tile i+1's 4 remain outstanding
        asm volatile("s_waitcnt vmcnt(4)" ::: "memory");
        // every wave's tile-i DMAs have landed -> tile i fully visible
        __builtin_amdgcn_s_barrier();

        const ushort* kc = kl[c];
        const ushort* vc = vl[c];

        // QK^T + exp2 + P to wave-private LDS
        #pragma unroll
        for (int nt = 0; nt < 4; ++nt) {
            const int krow = nt * 16 + m;
            bf16x8 b0 = *(const bf16x8*)&kc[krow * 64 + ((quad       ^ mx) * 8)];
            bf16x8 b1 = *(const bf16x8*)&kc[krow * 64 + (((4 + quad) ^ mx) * 8)];
            #pragma unroll
            for (int g = 0; g < 2; ++g) {
                f32x4 s = (f32x4){0.f, 0.f, 0.f, 0.f};
                s = __builtin_amdgcn_mfma_f32_16x16x32_bf16(qf[g][0], b0, s, 0, 0, 0);
                s = __builtin_amdgcn_mfma_f32_16x16x32_bf16(qf[g][1], b1, s, 0, 0, 0);
                #pragma unroll
                for (int r = 0; r < 4; ++r) {
                    float p = __builtin_amdgcn_exp2f(s[r]);
                    lsum[g][r] += p;
                    const int qrow = quad * 4 + r;
                    pw[(g * 16 + qrow) * 64
                       + (((nt * 2 + (m >> 3)) ^ (qrow & 7)) * 8) + mx] = f2bf_rhu(p);
                }
            }
        }

        // PV: A from wave-private P, B from swizzled Vt tile
        bf16x8 af[2][2];
        #pragma unroll
        for (int g = 0; g < 2; ++g) {
            af[g][0] = *(const bf16x8*)&pw[(g * 16 + m) * 64 + ((quad       ^ mx) * 8)];
            af[g][1] = *(const bf16x8*)&pw[(g * 16 + m) * 64 + (((4 + quad) ^ mx) * 8)];
        }
        #pragma unroll
        for (int nt = 0; nt < 4; ++nt) {
            const int vrow = nt * 16 + m;
            bf16x8 v0 = *(const bf16x8*)&vc[vrow * 64 + ((quad       ^ mx) * 8)];
            bf16x8 v1 = *(const bf16x8*)&vc[vrow * 64 + (((4 + quad) ^ mx) * 8)];
            #pragma unroll
            for (int g = 0; g < 2; ++g) {
                oa[g][nt] = __builtin_amdgcn_mfma_f32_16x16x32_bf16(af[g][0], v0, oa[g][nt], 0, 0, 0);
                oa[g][nt] = __builtin_amdgcn_mfma_f32_16x16x32_bf16(af[g][1], v1, oa[g][nt], 0, 0, 0);
            }
        }
    }

    #pragma unroll
    for (int g = 0; g < 2; ++g)
        #pragma unroll
        for (int r = 0; r < 4; ++r) {
            #pragma unroll
            for (int d = 1; d < 16; d <<= 1)
                lsum[g][r] += __shfl_xor(lsum[g][r], d, 64);
            lsum[g][r] = 1.0f / lsum[g][r];
        }

    const int b = bh >> 4, h = bh & 15;
    #pragma unroll
    for (int g = 0; g < 2; ++g)
        #pragma unroll
        for (int nt = 0; nt < 4; ++nt)
            #pragma unroll
            for (int r = 0; r < 4; ++r)
                O[((size_t)(b * Tv + q0 + wave * 32 + g * 16 + quad * 4 + r)) * Ev
                  + h * Sv + nt * 16 + m] = f2bf(oa[g][nt][r] * lsum[g][r]);
}

// ---------------------------------------------------------------------------
// Kernel 3: output projection, bf16 MFMA (m97 structure). (unchanged)
// ---------------------------------------------------------------------------
__global__ __launch_bounds__(256) void proj_kernel(
    const ushort* __restrict__ A, const ushort* __restrict__ B,
    const float* __restrict__ bp, float* __restrict__ C)
{
    __shared__ ushort Asm[128 * 32];
    __shared__ ushort Bsm[128 * 32];
    const int tid  = threadIdx.x;
    const int wave = tid >> 6;
    const int lane = tid & 63;
    const int m    = lane & 15;
    const int quad = lane >> 4;
    const int wm   = wave >> 1;
    const int wn   = wave & 1;
    const int m0   = blockIdx.x * 128;
    const int n0   = blockIdx.y * 128;

    f32x4 acc[4][4];
    #pragma unroll
    for (int i = 0; i < 4; ++i)
        #pragma unroll
        for (int j = 0; j < 4; ++j)
            acc[i][j] = (f32x4){0.f, 0.f, 0.f, 0.f};

    for (int k0 = 0; k0 < Ev; k0 += 32) {
        __syncthreads();
        #pragma unroll
        for (int j = 0; j < 2; ++j) {
            int c   = j * 256 + tid;
            int row = c >> 2;
            int col = (c & 3) * 8;
            async16(&Asm[c * 8], &A[(size_t)(m0 + row) * Ev + k0 + col]);
            async16(&Bsm[c * 8], &B[(size_t)(n0 + row) * Ev + k0 + col]);
        }
        __syncthreads();

        bf16x8 af[4], bf[4];
        #pragma unroll
        for (int i = 0; i < 4; ++i)
            af[i] = *(const bf16x8*)&Asm[(wm * 64 + i * 16 + m) * 32 + quad * 8];
        #pragma unroll
        for (int j = 0; j < 4; ++j)
            bf[j] = *(const bf16x8*)&Bsm[(wn * 64 + j * 16 + m) * 32 + quad * 8];
        #pragma unroll
        for (int i = 0; i < 4; ++i)
            #pragma unroll
            for (int j = 0; j < 4; ++j)
                acc[i][j] = __builtin_amdgcn_mfma_f32_16x16x32_bf16(
                    af[i], bf[j], acc[i][j], 0, 0, 0);
    }

    float bbv[4];
    #pragma unroll
    for (int j = 0; j < 4; ++j)
        bbv[j] = bp[n0 + wn * 64 + j * 16 + m];

    #pragma unroll
    for (int i = 0; i < 4; ++i)
        #pragma unroll
        for (int j = 0; j < 4; ++j)
            #pragma unroll
            for (int r = 0; r < 4; ++r)
                C[(size_t)(m0 + wm * 64 + i * 16 + quad * 4 + r) * Ev
                  + n0 + wn * 64 + j * 16 + m] = acc[i][j][r] + bbv[j];
}

// ---------------------------------------------------------------------------
// ws layout (ushort units):
//   Q 8.4M | K 8.4M | Vt 8.4M | O 8.4M | Wpb 1M | Wqb 4096 | Wkb 4096 | Wvb 4096
// ---------------------------------------------------------------------------
extern "C" void kernel_launch(void* const* d_in, const int* in_sizes, int n_in,
                              void* d_out, int out_size, void* d_ws, size_t ws_size,
                              hipStream_t stream) {
    const float* x  = (const float*)d_in[0];
    const float* Wk = (const float*)d_in[1];
    const float* Wq = (const float*)d_in[2];
    const float* Wv = (const float*)d_in[3];
    const float* Wp = (const float*)d_in[4];
    const float* bp = (const float*)d_in[5];
    float* out = (float*)d_out;

    ushort* Q   = (ushort*)d_ws;
    ushort* K   = Q   + 8388608;
    ushort* Vt  = K   + 8388608;
    ushort* O   = Vt  + 8388608;
    ushort* Wpb = O   + 8388608;
    ushort* Wqb = Wpb + 1048576;
    ushort* Wkb = Wqb + 4096;
    ushort* Wvb = Wkb + 4096;

    cast_kernel<<<1027, 256, 0, stream>>>(Wp, Wq, Wk, Wv, Wpb, Wqb, Wkb, Wvb);
    qkv_kernel<<<2048, 192, 0, stream>>>(x, Wqb, Wkb, Wvb, Q, K, Vt);
    attn_kernel<<<1024, 256, 0, stream>>>(Q, K, Vt, O);
    proj_kernel<<<dim3(64, 8), 256, 0, stream>>>(O, Wpb, bp, out);
}

// Round 9
// 229.564 us; speedup vs baseline: 1.6522x; 1.1178x over previous
//
#include <hip/hip_runtime.h>

#define Bv 4
#define Tv 2048
#define Ev 1024
#define Hv 16
#define Sv 64

typedef __attribute__((ext_vector_type(8))) short bf16x8;
typedef __attribute__((ext_vector_type(4))) float f32x4;

__device__ __forceinline__ ushort f2bf(float f) {
    unsigned u = __float_as_uint(f);
    u = (u + 0x7FFFu + ((u >> 16) & 1u)) >> 16;
    return (ushort)u;
}
__device__ __forceinline__ unsigned pk2(float a, float b) {
    return (unsigned)f2bf(a) | ((unsigned)f2bf(b) << 16);
}
// round-half-up packed pair (5 VALU), for softmax weights
__device__ __forceinline__ unsigned pk2r(float a, float b) {
    return ((__float_as_uint(a) + 0x8000u) >> 16)
         | ((__float_as_uint(b) + 0x8000u) & 0xffff0000u);
}

// async global->LDS, 16B per lane (global_load_lds_dwordx4)
__device__ __forceinline__ void async16(void* lds, const void* g) {
    __builtin_amdgcn_global_load_lds(
        (const __attribute__((address_space(1))) unsigned int*)g,
        (__attribute__((address_space(3))) unsigned int*)lds, 16, 0, 0);
}

// ---------------------------------------------------------------------------
// Kernel 0: cast weights fp32 -> bf16. Blocks 0..1023: Wp. 1024..1026: Wq/Wk/Wv
// Wq folded with (1/32)*log2(e): attn uses exp2 so v_exp_f32 needs no mul.
// ---------------------------------------------------------------------------
__global__ __launch_bounds__(256) void cast_kernel(
    const float* __restrict__ Wp, const float* __restrict__ Wq,
    const float* __restrict__ Wk, const float* __restrict__ Wv,
    ushort* __restrict__ Wpb, ushort* __restrict__ Wqb,
    ushort* __restrict__ Wkb, ushort* __restrict__ Wvb)
{
    int blk = blockIdx.x;
    if (blk < 1024) {
        int i = (blk * 256 + threadIdx.x) * 4;
        float4 v = *(const float4*)(Wp + i);
        ushort4 o;
        o.x = f2bf(v.x); o.y = f2bf(v.y); o.z = f2bf(v.z); o.w = f2bf(v.w);
        *(ushort4*)(Wpb + i) = o;
    } else {
        int p = blk - 1024;
        const float* src = (p == 0) ? Wq : ((p == 1) ? Wk : Wv);
        ushort* dst      = (p == 0) ? Wqb : ((p == 1) ? Wkb : Wvb);
        const float scale = (p == 0) ? 0.03125f * 1.4426950408889634f : 1.0f;
        #pragma unroll
        for (int it = 0; it < 4; ++it) {
            int i = (it * 256 + threadIdx.x) * 4;
            float4 v = *(const float4*)(src + i);
            ushort4 o;
            o.x = f2bf(v.x * scale); o.y = f2bf(v.y * scale);
            o.z = f2bf(v.z * scale); o.w = f2bf(v.w * scale);
            *(ushort4*)(dst + i) = o;
        }
    }
}

// ---------------------------------------------------------------------------
// Kernel 1: QKV projection via MFMA, no LDS. (unchanged from round 5)
// ---------------------------------------------------------------------------
__global__ __launch_bounds__(192) void qkv_kernel(
    const float* __restrict__ x,
    const ushort* __restrict__ Wqb, const ushort* __restrict__ Wkb,
    const ushort* __restrict__ Wvb,
    ushort* __restrict__ Q, ushort* __restrict__ K, ushort* __restrict__ Vt)
{
    const int tid  = threadIdx.x;
    const int wave = tid >> 6;        // 0=Q 1=K 2=V
    const int lane = tid & 63;
    const int m    = lane & 15;
    const int quad = lane >> 4;

    const ushort* Wsel = (wave == 0) ? Wqb : ((wave == 1) ? Wkb : Wvb);
    bf16x8 wf[4][2];
    #pragma unroll
    for (int ot = 0; ot < 4; ++ot)
        #pragma unroll
        for (int ks = 0; ks < 2; ++ks)
            wf[ot][ks] = *(const bf16x8*)&Wsel[(ot * 16 + m) * 64 + ks * 32 + quad * 8];

    const int tt = blockIdx.x >> 2;   // 0..511 token tile
    const int hg = blockIdx.x & 3;    // head group
    const int g0 = tt * 16;
    const int gm = g0 + m;
    const int b  = g0 >> 11;
    const int t0 = g0 & 2047;

    #pragma unroll
    for (int hi = 0; hi < 4; ++hi) {
        const int h  = hg * 4 + hi;
        const int bh = b * Hv + h;

        bf16x8 xf[2];
        #pragma unroll
        for (int ks = 0; ks < 2; ++ks) {
            const float* src = x + (size_t)gm * Ev + h * Sv + ks * 32 + quad * 8;
            float4 v0 = *(const float4*)src;
            float4 v1 = *(const float4*)(src + 4);
            unsigned pk[4];
            pk[0] = pk2(v0.x, v0.y); pk[1] = pk2(v0.z, v0.w);
            pk[2] = pk2(v1.x, v1.y); pk[3] = pk2(v1.z, v1.w);
            xf[ks] = *(bf16x8*)pk;
        }

        f32x4 acc[4];
        #pragma unroll
        for (int ot = 0; ot < 4; ++ot) acc[ot] = (f32x4){0.f, 0.f, 0.f, 0.f};

        if (wave < 2) {
            #pragma unroll
            for (int ks = 0; ks < 2; ++ks)
                #pragma unroll
                for (int ot = 0; ot < 4; ++ot)
                    acc[ot] = __builtin_amdgcn_mfma_f32_16x16x32_bf16(
                        wf[ot][ks], xf[ks], acc[ot], 0, 0, 0);
            ushort* dst = ((wave == 0) ? Q : K)
                        + ((size_t)bh * Tv + t0 + m) * Sv + quad * 4;
            #pragma unroll
            for (int ot = 0; ot < 4; ++ot) {
                uint2 w;
                w.x = pk2(acc[ot][0], acc[ot][1]);
                w.y = pk2(acc[ot][2], acc[ot][3]);
                *(uint2*)(dst + ot * 16) = w;
            }
        } else {
            #pragma unroll
            for (int ks = 0; ks < 2; ++ks)
                #pragma unroll
                for (int st = 0; st < 4; ++st)
                    acc[st] = __builtin_amdgcn_mfma_f32_16x16x32_bf16(
                        xf[ks], wf[st][ks], acc[st], 0, 0, 0);
            ushort* vr = Vt + ((size_t)bh * Sv + m) * Tv + t0 + quad * 4;
            #pragma unroll
            for (int st = 0; st < 4; ++st) {
                uint2 w;
                w.x = pk2(acc[st][0], acc[st][1]);
                w.y = pk2(acc[st][2], acc[st][3]);
                *(uint2*)(vr + (size_t)st * 16 * Tv) = w;
            }
        }
    }
}

// ---------------------------------------------------------------------------
// Kernel 2: flash attention v6 — R5 structure + S^T trick.
// QK^T computed TRANSPOSED: S^T = K·Q^T (A = K rows from LDS, B = Q frags
// from registers — same data, swapped operands). D then gives each lane 4
// CONSECUTIVE keys for one query -> P written as 8 ds_write_b64 per tile
// instead of 32 scalar ds_write_b16 (the LDS-pipe hot spot: ~474 cyc/tile
// -> ~352). P lands in [q][key] layout = exactly PV's A-frag source.
// lsum becomes per-lane-per-query: 2 shuffles, LDS bounce in epilogue.
// Single-buffered staging (32KB LDS) — R6/R8 proved pipelining regressions.
// ---------------------------------------------------------------------------
__global__ __launch_bounds__(256, 4) void attn_kernel(
    const ushort* __restrict__ Q, const ushort* __restrict__ K,
    const ushort* __restrict__ Vt, ushort* __restrict__ O)
{
    __shared__ ushort kl[64 * 64];        // K tile  [key][d]   (swizzled)
    __shared__ ushort vl[64 * 64];        // Vt tile [s][key]   (swizzled)
    __shared__ ushort pl[4][32 * 64];     // P per wave [q][key] (swizzled)

    const int tid  = threadIdx.x;
    const int wave = tid >> 6;
    const int lane = tid & 63;
    const int m    = lane & 15;
    const int quad = lane >> 4;
    const int bh   = blockIdx.x & 63;
    const int q0   = (blockIdx.x >> 6) << 7;   // query tile base (128)

    // Q fragments (used as B-operand of S^T = K·Q^T): rows q = ..+g*16+m
    const ushort* Qb = Q + ((size_t)bh * Tv + q0 + wave * 32) * Sv;
    bf16x8 qf[2][2];
    #pragma unroll
    for (int g = 0; g < 2; ++g)
        #pragma unroll
        for (int ks = 0; ks < 2; ++ks)
            qf[g][ks] = *(const bf16x8*)&Qb[(g * 16 + m) * Sv + ks * 32 + quad * 8];

    f32x4 oa[2][4];
    float lsum[2] = {0.f, 0.f};
    #pragma unroll
    for (int g = 0; g < 2; ++g)
        #pragma unroll
        for (int nt = 0; nt < 4; ++nt)
            oa[g][nt] = (f32x4){0.f, 0.f, 0.f, 0.f};

    const ushort* Kb = K  + (size_t)bh * Tv * Sv;
    const ushort* Vb = Vt + (size_t)bh * Sv * Tv;
    ushort* pw = pl[wave];

    // staging geometry (swizzled): chunk c -> row=c>>3, phys cg=c&7,
    // source col-group = (c&7) ^ (row&7)
    const int r0 = tid >> 3,         cg0 = (tid & 7) ^ (r0 & 7);
    const int r1 = (256 + tid) >> 3, cg1 = ((256 + tid) & 7) ^ (r1 & 7);
    const size_t koff0 = (size_t)r0 * Sv + cg0 * 8;
    const size_t koff1 = (size_t)r1 * Sv + cg1 * 8;
    const size_t voff0 = (size_t)r0 * Tv + cg0 * 8;
    const size_t voff1 = (size_t)r1 * Tv + cg1 * 8;
    const int mx = m & 7;

    for (int k0 = 0; k0 < Tv; k0 += 64) {
        __syncthreads();
        async16(&kl[(size_t)tid * 8],         Kb + (size_t)k0 * Sv + koff0);
        async16(&kl[((size_t)tid + 256) * 8], Kb + (size_t)k0 * Sv + koff1);
        async16(&vl[(size_t)tid * 8],         Vb + k0 + voff0);
        async16(&vl[((size_t)tid + 256) * 8], Vb + k0 + voff1);
        __syncthreads();

        // S^T = K·Q^T -> exp2 -> packed b64 P-writes ([q][key] layout)
        #pragma unroll
        for (int nt = 0; nt < 4; ++nt) {
            const int krow = nt * 16 + m;
            bf16x8 a0 = *(const bf16x8*)&kl[krow * 64 + ((quad       ^ mx) * 8)];
            bf16x8 a1 = *(const bf16x8*)&kl[krow * 64 + (((4 + quad) ^ mx) * 8)];
            #pragma unroll
            for (int g = 0; g < 2; ++g) {
                f32x4 s = (f32x4){0.f, 0.f, 0.f, 0.f};
                s = __builtin_amdgcn_mfma_f32_16x16x32_bf16(a0, qf[g][0], s, 0, 0, 0);
                s = __builtin_amdgcn_mfma_f32_16x16x32_bf16(a1, qf[g][1], s, 0, 0, 0);
                float p0 = __builtin_amdgcn_exp2f(s[0]);
                float p1 = __builtin_amdgcn_exp2f(s[1]);
                float p2 = __builtin_amdgcn_exp2f(s[2]);
                float p3 = __builtin_amdgcn_exp2f(s[3]);
                lsum[g] += (p0 + p1) + (p2 + p3);
                uint2 w;
                w.x = pk2r(p0, p1);
                w.y = pk2r(p2, p3);
                // keys nt*16+quad*4..+3 for query g*16+m: colgroup
                // nt*2+(quad>>1), phys = cg ^ mx, offset (quad&1)*4
                *(uint2*)&pw[(g * 16 + m) * 64
                             + (((nt * 2 + (quad >> 1)) ^ mx) * 8)
                             + (quad & 1) * 4] = w;
            }
        }

        // PV: A from wave-private P rows, B from swizzled Vt tile
        bf16x8 af[2][2];
        #pragma unroll
        for (int g = 0; g < 2; ++g) {
            af[g][0] = *(const bf16x8*)&pw[(g * 16 + m) * 64 + ((quad       ^ mx) * 8)];
            af[g][1] = *(const bf16x8*)&pw[(g * 16 + m) * 64 + (((4 + quad) ^ mx) * 8)];
        }
        #pragma unroll
        for (int nt = 0; nt < 4; ++nt) {
            const int vrow = nt * 16 + m;
            bf16x8 v0 = *(const bf16x8*)&vl[vrow * 64 + ((quad       ^ mx) * 8)];
            bf16x8 v1 = *(const bf16x8*)&vl[vrow * 64 + (((4 + quad) ^ mx) * 8)];
            #pragma unroll
            for (int g = 0; g < 2; ++g) {
                oa[g][nt] = __builtin_amdgcn_mfma_f32_16x16x32_bf16(af[g][0], v0, oa[g][nt], 0, 0, 0);
                oa[g][nt] = __builtin_amdgcn_mfma_f32_16x16x32_bf16(af[g][1], v1, oa[g][nt], 0, 0, 0);
            }
        }
    }

    // lsum: lane (m,quad) holds partial for query g*16+m over this quad's
    // keys; reduce across quads (bits 4,5), then bounce via wave-private LDS
    // to the (quad*4+r)-indexed consumers in the O store.
    #pragma unroll
    for (int g = 0; g < 2; ++g) {
        lsum[g] += __shfl_xor(lsum[g], 16, 64);
        lsum[g] += __shfl_xor(lsum[g], 32, 64);
    }
    float* ll = (float*)pw;               // pw is dead; reuse (wave-private)
    if (lane < 16) {
        ll[lane]      = 1.0f / lsum[0];
        ll[16 + lane] = 1.0f / lsum[1];
    }

    const int b = bh >> 4, h = bh & 15;
    #pragma unroll
    for (int g = 0; g < 2; ++g)
        #pragma unroll
        for (int nt = 0; nt < 4; ++nt)
            #pragma unroll
            for (int r = 0; r < 4; ++r)
                O[((size_t)(b * Tv + q0 + wave * 32 + g * 16 + quad * 4 + r)) * Ev
                  + h * Sv + nt * 16 + m]
                    = f2bf(oa[g][nt][r] * ll[g * 16 + quad * 4 + r]);
}

// ---------------------------------------------------------------------------
// Kernel 3: output projection, bf16 MFMA (m97 structure). (unchanged)
// ---------------------------------------------------------------------------
__global__ __launch_bounds__(256) void proj_kernel(
    const ushort* __restrict__ A, const ushort* __restrict__ B,
    const float* __restrict__ bp, float* __restrict__ C)
{
    __shared__ ushort Asm[128 * 32];
    __shared__ ushort Bsm[128 * 32];
    const int tid  = threadIdx.x;
    const int wave = tid >> 6;
    const int lane = tid & 63;
    const int m    = lane & 15;
    const int quad = lane >> 4;
    const int wm   = wave >> 1;
    const int wn   = wave & 1;
    const int m0   = blockIdx.x * 128;
    const int n0   = blockIdx.y * 128;

    f32x4 acc[4][4];
    #pragma unroll
    for (int i = 0; i < 4; ++i)
        #pragma unroll
        for (int j = 0; j < 4; ++j)
            acc[i][j] = (f32x4){0.f, 0.f, 0.f, 0.f};

    for (int k0 = 0; k0 < Ev; k0 += 32) {
        __syncthreads();
        #pragma unroll
        for (int j = 0; j < 2; ++j) {
            int c   = j * 256 + tid;
            int row = c >> 2;
            int col = (c & 3) * 8;
            async16(&Asm[c * 8], &A[(size_t)(m0 + row) * Ev + k0 + col]);
            async16(&Bsm[c * 8], &B[(size_t)(n0 + row) * Ev + k0 + col]);
        }
        __syncthreads();

        bf16x8 af[4], bf[4];
        #pragma unroll
        for (int i = 0; i < 4; ++i)
            af[i] = *(const bf16x8*)&Asm[(wm * 64 + i * 16 + m) * 32 + quad * 8];
        #pragma unroll
        for (int j = 0; j < 4; ++j)
            bf[j] = *(const bf16x8*)&Bsm[(wn * 64 + j * 16 + m) * 32 + quad * 8];
        #pragma unroll
        for (int i = 0; i < 4; ++i)
            #pragma unroll
            for (int j = 0; j < 4; ++j)
                acc[i][j] = __builtin_amdgcn_mfma_f32_16x16x32_bf16(
                    af[i], bf[j], acc[i][j], 0, 0, 0);
    }

    float bbv[4];
    #pragma unroll
    for (int j = 0; j < 4; ++j)
        bbv[j] = bp[n0 + wn * 64 + j * 16 + m];

    #pragma unroll
    for (int i = 0; i < 4; ++i)
        #pragma unroll
        for (int j = 0; j < 4; ++j)
            #pragma unroll
            for (int r = 0; r < 4; ++r)
                C[(size_t)(m0 + wm * 64 + i * 16 + quad * 4 + r) * Ev
                  + n0 + wn * 64 + j * 16 + m] = acc[i][j][r] + bbv[j];
}

// ---------------------------------------------------------------------------
// ws layout (ushort units):
//   Q 8.4M | K 8.4M | Vt 8.4M | O 8.4M | Wpb 1M | Wqb 4096 | Wkb 4096 | Wvb 4096
// ---------------------------------------------------------------------------
extern "C" void kernel_launch(void* const* d_in, const int* in_sizes, int n_in,
                              void* d_out, int out_size, void* d_ws, size_t ws_size,
                              hipStream_t stream) {
    const float* x  = (const float*)d_in[0];
    const float* Wk = (const float*)d_in[1];
    const float* Wq = (const float*)d_in[2];
    const float* Wv = (const float*)d_in[3];
    const float* Wp = (const float*)d_in[4];
    const float* bp = (const float*)d_in[5];
    float* out = (float*)d_out;

    ushort* Q   = (ushort*)d_ws;
    ushort* K   = Q   + 8388608;
    ushort* Vt  = K   + 8388608;
    ushort* O   = Vt  + 8388608;
    ushort* Wpb = O   + 8388608;
    ushort* Wqb = Wpb + 1048576;
    ushort* Wkb = Wqb + 4096;
    ushort* Wvb = Wkb + 4096;

    cast_kernel<<<1027, 256, 0, stream>>>(Wp, Wq, Wk, Wv, Wpb, Wqb, Wkb, Wvb);
    qkv_kernel<<<2048, 192, 0, stream>>>(x, Wqb, Wkb, Wvb, Q, K, Vt);
    attn_kernel<<<1024, 256, 0, stream>>>(Q, K, Vt, O);
    proj_kernel<<<dim3(64, 8), 256, 0, stream>>>(O, Wpb, bp, out);
}

// Round 10
// 223.616 us; speedup vs baseline: 1.6962x; 1.0266x over previous
//
#include <hip/hip_runtime.h>
#include <hip/hip_bf16.h>

#define Bv 4
#define Tv 2048
#define Ev 1024
#define Hv 16
#define Sv 64

typedef __attribute__((ext_vector_type(8))) short bf16x8;
typedef __attribute__((ext_vector_type(4))) short bf16x4;
typedef __attribute__((ext_vector_type(4))) float f32x4;

// 16x16x16 bf16 MFMA (A/B = 4 bf16 = 2 VGPR) — builtin name varies by ROCm
#if __has_builtin(__builtin_amdgcn_mfma_f32_16x16x16_bf16)
#define MFMA161616(a, b, c) __builtin_amdgcn_mfma_f32_16x16x16_bf16(a, b, c, 0, 0, 0)
#elif __has_builtin(__builtin_amdgcn_mfma_f32_16x16x16bf16_1k)
#define MFMA161616(a, b, c) __builtin_amdgcn_mfma_f32_16x16x16bf16_1k(a, b, c, 0, 0, 0)
#else
__device__ __forceinline__ f32x4 mfma161616_asm(bf16x4 a, bf16x4 b, f32x4 c) {
    f32x4 d;
    asm("v_mfma_f32_16x16x16_bf16 %0, %1, %2, %3" : "=v"(d) : "v"(a), "v"(b), "v"(c));
    return d;
}
#define MFMA161616(a, b, c) mfma161616_asm(a, b, c)
#endif

__device__ __forceinline__ ushort f2bf(float f) {
    unsigned u = __float_as_uint(f);
    u = (u + 0x7FFFu + ((u >> 16) & 1u)) >> 16;
    return (ushort)u;
}
// RNE pack via v_cvt_pk_bf16_f32 (header lowers to HW instr on gfx950)
__device__ __forceinline__ unsigned pkrn(float a, float b) {
    __hip_bfloat162 t = __float22bfloat162_rn(make_float2(a, b));
    unsigned r; __builtin_memcpy(&r, &t, 4); return r;
}
// truncation pack, 1 VALU op (v_perm_b32): {lo=a_trunc, hi=b_trunc}
__device__ __forceinline__ unsigned pktr(float a, float b) {
    return __builtin_amdgcn_perm(__float_as_uint(b), __float_as_uint(a), 0x07060302u);
}

// async global->LDS, 16B per lane (global_load_lds_dwordx4)
__device__ __forceinline__ void async16(void* lds, const void* g) {
    __builtin_amdgcn_global_load_lds(
        (const __attribute__((address_space(1))) unsigned int*)g,
        (__attribute__((address_space(3))) unsigned int*)lds, 16, 0, 0);
}

// ---------------------------------------------------------------------------
// Kernel 0: cast weights fp32 -> bf16. Blocks 0..1023: Wp. 1024..1026: Wq/Wk/Wv
// Wq folded with (1/32)*log2(e): attn uses exp2 so v_exp_f32 needs no mul.
// ---------------------------------------------------------------------------
__global__ __launch_bounds__(256) void cast_kernel(
    const float* __restrict__ Wp, const float* __restrict__ Wq,
    const float* __restrict__ Wk, const float* __restrict__ Wv,
    ushort* __restrict__ Wpb, ushort* __restrict__ Wqb,
    ushort* __restrict__ Wkb, ushort* __restrict__ Wvb)
{
    int blk = blockIdx.x;
    if (blk < 1024) {
        int i = (blk * 256 + threadIdx.x) * 4;
        float4 v = *(const float4*)(Wp + i);
        uint2 o = {pkrn(v.x, v.y), pkrn(v.z, v.w)};
        *(uint2*)(Wpb + i) = o;
    } else {
        int p = blk - 1024;
        const float* src = (p == 0) ? Wq : ((p == 1) ? Wk : Wv);
        ushort* dst      = (p == 0) ? Wqb : ((p == 1) ? Wkb : Wvb);
        const float scale = (p == 0) ? 0.03125f * 1.4426950408889634f : 1.0f;
        #pragma unroll
        for (int it = 0; it < 4; ++it) {
            int i = (it * 256 + threadIdx.x) * 4;
            float4 v = *(const float4*)(src + i);
            uint2 o = {pkrn(v.x * scale, v.y * scale), pkrn(v.z * scale, v.w * scale)};
            *(uint2*)(dst + i) = o;
        }
    }
}

// ---------------------------------------------------------------------------
// Kernel 1: QKV projection via MFMA, no LDS. (R5 structure; packs via
// v_cvt_pk_bf16_f32 instead of 9-op manual RNE)
// ---------------------------------------------------------------------------
__global__ __launch_bounds__(192) void qkv_kernel(
    const float* __restrict__ x,
    const ushort* __restrict__ Wqb, const ushort* __restrict__ Wkb,
    const ushort* __restrict__ Wvb,
    ushort* __restrict__ Q, ushort* __restrict__ K, ushort* __restrict__ Vt)
{
    const int tid  = threadIdx.x;
    const int wave = tid >> 6;        // 0=Q 1=K 2=V
    const int lane = tid & 63;
    const int m    = lane & 15;
    const int quad = lane >> 4;

    const ushort* Wsel = (wave == 0) ? Wqb : ((wave == 1) ? Wkb : Wvb);
    bf16x8 wf[4][2];
    #pragma unroll
    for (int ot = 0; ot < 4; ++ot)
        #pragma unroll
        for (int ks = 0; ks < 2; ++ks)
            wf[ot][ks] = *(const bf16x8*)&Wsel[(ot * 16 + m) * 64 + ks * 32 + quad * 8];

    const int tt = blockIdx.x >> 2;   // 0..511 token tile
    const int hg = blockIdx.x & 3;    // head group
    const int g0 = tt * 16;
    const int gm = g0 + m;
    const int b  = g0 >> 11;
    const int t0 = g0 & 2047;

    #pragma unroll
    for (int hi = 0; hi < 4; ++hi) {
        const int h  = hg * 4 + hi;
        const int bh = b * Hv + h;

        bf16x8 xf[2];
        #pragma unroll
        for (int ks = 0; ks < 2; ++ks) {
            const float* src = x + (size_t)gm * Ev + h * Sv + ks * 32 + quad * 8;
            float4 v0 = *(const float4*)src;
            float4 v1 = *(const float4*)(src + 4);
            unsigned pk[4];
            pk[0] = pkrn(v0.x, v0.y); pk[1] = pkrn(v0.z, v0.w);
            pk[2] = pkrn(v1.x, v1.y); pk[3] = pkrn(v1.z, v1.w);
            xf[ks] = *(bf16x8*)pk;
        }

        f32x4 acc[4];
        #pragma unroll
        for (int ot = 0; ot < 4; ++ot) acc[ot] = (f32x4){0.f, 0.f, 0.f, 0.f};

        if (wave < 2) {
            #pragma unroll
            for (int ks = 0; ks < 2; ++ks)
                #pragma unroll
                for (int ot = 0; ot < 4; ++ot)
                    acc[ot] = __builtin_amdgcn_mfma_f32_16x16x32_bf16(
                        wf[ot][ks], xf[ks], acc[ot], 0, 0, 0);
            ushort* dst = ((wave == 0) ? Q : K)
                        + ((size_t)bh * Tv + t0 + m) * Sv + quad * 4;
            #pragma unroll
            for (int ot = 0; ot < 4; ++ot) {
                uint2 w = {pkrn(acc[ot][0], acc[ot][1]), pkrn(acc[ot][2], acc[ot][3])};
                *(uint2*)(dst + ot * 16) = w;
            }
        } else {
            #pragma unroll
            for (int ks = 0; ks < 2; ++ks)
                #pragma unroll
                for (int st = 0; st < 4; ++st)
                    acc[st] = __builtin_amdgcn_mfma_f32_16x16x32_bf16(
                        xf[ks], wf[st][ks], acc[st], 0, 0, 0);
            ushort* vr = Vt + ((size_t)bh * Sv + m) * Tv + t0 + quad * 4;
            #pragma unroll
            for (int st = 0; st < 4; ++st) {
                uint2 w = {pkrn(acc[st][0], acc[st][1]), pkrn(acc[st][2], acc[st][3])};
                *(uint2*)(vr + (size_t)st * 16 * Tv) = w;
            }
        }
    }
}

// ---------------------------------------------------------------------------
// Kernel 2: flash attention v7 — P LIVES IN REGISTERS.
// S^T = K·Q^T via 16x16x32 puts P in lane (m,quad) as [q=g*16+m][keys
// quad*4+r] per 16-key tile — exactly the A-frag layout of
// v_mfma_f32_16x16x16_bf16. PV = 32 16x16x16 MFMAs consuming P from regs:
// no P LDS write/read at all (R9's DS hot spot: 336->~230 cy/wave-tile).
// Vt B-frags = b64 reads from the swizzled vl tile (same staging as R9).
// P packed by 1-op v_perm truncation. LDS 16.5KB; pl eliminated.
// ---------------------------------------------------------------------------
__global__ __launch_bounds__(256, 4) void attn_kernel(
    const ushort* __restrict__ Q, const ushort* __restrict__ K,
    const ushort* __restrict__ Vt, ushort* __restrict__ O)
{
    __shared__ ushort kl[64 * 64];        // K tile  [key][d]   (swizzled)
    __shared__ ushort vl[64 * 64];        // Vt tile [s][key]   (swizzled)
    __shared__ float  ll[4][32];          // per-wave 1/lsum bounce

    const int tid  = threadIdx.x;
    const int wave = tid >> 6;
    const int lane = tid & 63;
    const int m    = lane & 15;
    const int quad = lane >> 4;
    const int bh   = blockIdx.x & 63;
    const int q0   = (blockIdx.x >> 6) << 7;   // query tile base (128)

    // Q fragments (B-operand of S^T = K·Q^T)
    const ushort* Qb = Q + ((size_t)bh * Tv + q0 + wave * 32) * Sv;
    bf16x8 qf[2][2];
    #pragma unroll
    for (int g = 0; g < 2; ++g)
        #pragma unroll
        for (int ks = 0; ks < 2; ++ks)
            qf[g][ks] = *(const bf16x8*)&Qb[(g * 16 + m) * Sv + ks * 32 + quad * 8];

    f32x4 oa[2][4];
    float lsum[2] = {0.f, 0.f};
    #pragma unroll
    for (int g = 0; g < 2; ++g)
        #pragma unroll
        for (int st = 0; st < 4; ++st)
            oa[g][st] = (f32x4){0.f, 0.f, 0.f, 0.f};

    const ushort* Kb = K  + (size_t)bh * Tv * Sv;
    const ushort* Vb = Vt + (size_t)bh * Sv * Tv;

    // staging geometry (swizzled): chunk c -> row=c>>3, phys cg=c&7,
    // source col-group = (c&7) ^ (row&7)
    const int r0 = tid >> 3,         cg0 = (tid & 7) ^ (r0 & 7);
    const int r1 = (256 + tid) >> 3, cg1 = ((256 + tid) & 7) ^ (r1 & 7);
    const size_t koff0 = (size_t)r0 * Sv + cg0 * 8;
    const size_t koff1 = (size_t)r1 * Sv + cg1 * 8;
    const size_t voff0 = (size_t)r0 * Tv + cg0 * 8;
    const size_t voff1 = (size_t)r1 * Tv + cg1 * 8;
    const int mx = m & 7;

    for (int k0 = 0; k0 < Tv; k0 += 64) {
        __syncthreads();
        async16(&kl[(size_t)tid * 8],         Kb + (size_t)k0 * Sv + koff0);
        async16(&kl[((size_t)tid + 256) * 8], Kb + (size_t)k0 * Sv + koff1);
        async16(&vl[(size_t)tid * 8],         Vb + k0 + voff0);
        async16(&vl[((size_t)tid + 256) * 8], Vb + k0 + voff1);
        __syncthreads();

        // S^T = K·Q^T -> exp2 -> P packed into registers (A-frag layout
        // of 16x16x16: lane (m,quad) = P[q=g*16+m][key=nt*16+quad*4+j])
        bf16x4 w[4][2];
        #pragma unroll
        for (int nt = 0; nt < 4; ++nt) {
            const int krow = nt * 16 + m;
            bf16x8 a0 = *(const bf16x8*)&kl[krow * 64 + ((quad       ^ mx) * 8)];
            bf16x8 a1 = *(const bf16x8*)&kl[krow * 64 + (((4 + quad) ^ mx) * 8)];
            #pragma unroll
            for (int g = 0; g < 2; ++g) {
                f32x4 s = (f32x4){0.f, 0.f, 0.f, 0.f};
                s = __builtin_amdgcn_mfma_f32_16x16x32_bf16(a0, qf[g][0], s, 0, 0, 0);
                s = __builtin_amdgcn_mfma_f32_16x16x32_bf16(a1, qf[g][1], s, 0, 0, 0);
                float p0 = __builtin_amdgcn_exp2f(s[0]);
                float p1 = __builtin_amdgcn_exp2f(s[1]);
                float p2 = __builtin_amdgcn_exp2f(s[2]);
                float p3 = __builtin_amdgcn_exp2f(s[3]);
                lsum[g] += (p0 + p1) + (p2 + p3);
                unsigned pk[2] = {pktr(p0, p1), pktr(p2, p3)};
                w[nt][g] = *(bf16x4*)pk;
            }
        }

        // PV via 16x16x16: A = w (registers), B = Vt b64 frags from vl.
        // B-frag (st,kt): Vt_tile[s=st*16+m][keys kt*16+quad*4 ..+3]
        #pragma unroll
        for (int st = 0; st < 4; ++st) {
            const int srow = st * 16 + m;
            bf16x4 vf[4];
            #pragma unroll
            for (int kt = 0; kt < 4; ++kt)
                vf[kt] = *(const bf16x4*)&vl[srow * 64
                           + (((2 * kt + (quad >> 1)) ^ mx) * 8) + (quad & 1) * 4];
            #pragma unroll
            for (int g = 0; g < 2; ++g)
                #pragma unroll
                for (int kt = 0; kt < 4; ++kt)
                    oa[g][st] = MFMA161616(w[kt][g], vf[kt], oa[g][st]);
        }
    }

    // lsum: reduce across quads; redistribute 1/l via wave-private LDS
    #pragma unroll
    for (int g = 0; g < 2; ++g) {
        lsum[g] += __shfl_xor(lsum[g], 16, 64);
        lsum[g] += __shfl_xor(lsum[g], 32, 64);
    }
    if (lane < 16) {
        ll[wave][lane]      = 1.0f / lsum[0];
        ll[wave][16 + lane] = 1.0f / lsum[1];
    }

    const int b = bh >> 4, h = bh & 15;
    #pragma unroll
    for (int g = 0; g < 2; ++g)
        #pragma unroll
        for (int st = 0; st < 4; ++st)
            #pragma unroll
            for (int r = 0; r < 4; ++r)
                O[((size_t)(b * Tv + q0 + wave * 32 + g * 16 + quad * 4 + r)) * Ev
                  + h * Sv + st * 16 + m]
                    = f2bf(oa[g][st][r] * ll[wave][g * 16 + quad * 4 + r]);
}

// ---------------------------------------------------------------------------
// Kernel 3: output projection, bf16 MFMA (m97 structure). (unchanged)
// ---------------------------------------------------------------------------
__global__ __launch_bounds__(256) void proj_kernel(
    const ushort* __restrict__ A, const ushort* __restrict__ B,
    const float* __restrict__ bp, float* __restrict__ C)
{
    __shared__ ushort Asm[128 * 32];
    __shared__ ushort Bsm[128 * 32];
    const int tid  = threadIdx.x;
    const int wave = tid >> 6;
    const int lane = tid & 63;
    const int m    = lane & 15;
    const int quad = lane >> 4;
    const int wm   = wave >> 1;
    const int wn   = wave & 1;
    const int m0   = blockIdx.x * 128;
    const int n0   = blockIdx.y * 128;

    f32x4 acc[4][4];
    #pragma unroll
    for (int i = 0; i < 4; ++i)
        #pragma unroll
        for (int j = 0; j < 4; ++j)
            acc[i][j] = (f32x4){0.f, 0.f, 0.f, 0.f};

    for (int k0 = 0; k0 < Ev; k0 += 32) {
        __syncthreads();
        #pragma unroll
        for (int j = 0; j < 2; ++j) {
            int c   = j * 256 + tid;
            int row = c >> 2;
            int col = (c & 3) * 8;
            async16(&Asm[c * 8], &A[(size_t)(m0 + row) * Ev + k0 + col]);
            async16(&Bsm[c * 8], &B[(size_t)(n0 + row) * Ev + k0 + col]);
        }
        __syncthreads();

        bf16x8 af[4], bf[4];
        #pragma unroll
        for (int i = 0; i < 4; ++i)
            af[i] = *(const bf16x8*)&Asm[(wm * 64 + i * 16 + m) * 32 + quad * 8];
        #pragma unroll
        for (int j = 0; j < 4; ++j)
            bf[j] = *(const bf16x8*)&Bsm[(wn * 64 + j * 16 + m) * 32 + quad * 8];
        #pragma unroll
        for (int i = 0; i < 4; ++i)
            #pragma unroll
            for (int j = 0; j < 4; ++j)
                acc[i][j] = __builtin_amdgcn_mfma_f32_16x16x32_bf16(
                    af[i], bf[j], acc[i][j], 0, 0, 0);
    }

    float bbv[4];
    #pragma unroll
    for (int j = 0; j < 4; ++j)
        bbv[j] = bp[n0 + wn * 64 + j * 16 + m];

    #pragma unroll
    for (int i = 0; i < 4; ++i)
        #pragma unroll
        for (int j = 0; j < 4; ++j)
            #pragma unroll
            for (int r = 0; r < 4; ++r)
                C[(size_t)(m0 + wm * 64 + i * 16 + quad * 4 + r) * Ev
                  + n0 + wn * 64 + j * 16 + m] = acc[i][j][r] + bbv[j];
}

// ---------------------------------------------------------------------------
// ws layout (ushort units):
//   Q 8.4M | K 8.4M | Vt 8.4M | O 8.4M | Wpb 1M | Wqb 4096 | Wkb 4096 | Wvb 4096
// ---------------------------------------------------------------------------
extern "C" void kernel_launch(void* const* d_in, const int* in_sizes, int n_in,
                              void* d_out, int out_size, void* d_ws, size_t ws_size,
                              hipStream_t stream) {
    const float* x  = (const float*)d_in[0];
    const float* Wk = (const float*)d_in[1];
    const float* Wq = (const float*)d_in[2];
    const float* Wv = (const float*)d_in[3];
    const float* Wp = (const float*)d_in[4];
    const float* bp = (const float*)d_in[5];
    float* out = (float*)d_out;

    ushort* Q   = (ushort*)d_ws;
    ushort* K   = Q   + 8388608;
    ushort* Vt  = K   + 8388608;
    ushort* O   = Vt  + 8388608;
    ushort* Wpb = O   + 8388608;
    ushort* Wqb = Wpb + 1048576;
    ushort* Wkb = Wqb + 4096;
    ushort* Wvb = Wkb + 4096;

    cast_kernel<<<1027, 256, 0, stream>>>(Wp, Wq, Wk, Wv, Wpb, Wqb, Wkb, Wvb);
    qkv_kernel<<<2048, 192, 0, stream>>>(x, Wqb, Wkb, Wvb, Q, K, Vt);
    attn_kernel<<<1024, 256, 0, stream>>>(Q, K, Vt, O);
    proj_kernel<<<dim3(64, 8), 256, 0, stream>>>(O, Wpb, bp, out);
}